// Round 9
// baseline (41.876 us; speedup 1.0000x reference)
//
#include <hip/hip_runtime.h>
#include <hip/hip_bf16.h>

// EdgeNetwork: B=8, N=256, F_IN=64, F_OUT=64, MID=96
// out[b,n,o] = sum_m tanh( relu( [x_n, x_j(m), e_{b,n,m}] @ W1 + b1 ) @ W2 + b2 )[o]
// H[m,:] = A[b,n,:] + C[b,j(m),:] + e[m]*W1[128,:],  j = m + (m>=n)
// R9: neighbor-split. Block = (b, n-quad, m-half): stages 129 C rows (26.8 KB
// LDS), grid 1024 = 4 blocks/CU -> 12-16 waves/CU (was 8). Partials to ws,
// tiny combine kernel: out = 256 - 2*(P0+P1). Invalid slot m=255 -> r=0.5.

#define BATCH 8
#define NN 256
#define FIN 64
#define FOUT 64
#define MIDD 96
#define CPAD 104      // bf16 elems per padded row (208 B)
#define NG 4          // n-values per block
#define HROWS 129     // staged C rows per half (half0 needs j=0..128)

typedef __attribute__((ext_vector_type(8))) short short8;  // 8 bf16
typedef __attribute__((ext_vector_type(4))) float f32x4;

#if __has_builtin(__builtin_amdgcn_exp2f)
#define EXP2F(x) __builtin_amdgcn_exp2f(x)
#else
#define EXP2F(x) exp2f(x)
#endif
#if __has_builtin(__builtin_amdgcn_rcpf)
#define RCPF(x) __builtin_amdgcn_rcpf(x)
#else
#define RCPF(x) (1.0f / (x))
#endif

#define TWO_LOG2E 2.8853900817779268f

__device__ __forceinline__ unsigned pack_bf16(float lo, float hi) {
    __hip_bfloat162 h2 = __float22bfloat162_rn(make_float2(lo, hi));
    union { __hip_bfloat162 h; unsigned u; } cv; cv.h = h2;
    return cv.u;
}

// ------------- precompute: A (f32), C (bf16 padded), W2T (bf16 padded) -------
__global__ __launch_bounds__(192) void edge_pre(
    const float* __restrict__ node,    // (B,N,64)
    const float* __restrict__ W1,      // (129,96)
    const float* __restrict__ b1,      // (96,)
    const float* __restrict__ W2,      // (96,64)
    float* __restrict__ A,             // (B*N,96) f32
    unsigned short* __restrict__ Cb16, // (B,N,CPAD) bf16
    unsigned short* __restrict__ W2T)  // (64,CPAD) bf16
{
    int blk = blockIdx.x;
    int tid = threadIdx.x;
    if (blk == BATCH * NN) {
        for (int idx = tid; idx < FOUT * CPAD; idx += 192) {
            int c = idx / CPAD, k = idx % CPAD;
            float v = (k < MIDD) ? W2[k * FOUT + c] : 0.f;
            union { __hip_bfloat16 h; unsigned short u; } cv;
            cv.h = __float2bfloat16(v);
            W2T[idx] = cv.u;
        }
        return;
    }
    __shared__ float x[FIN];
    if (tid < FIN) x[tid] = node[(size_t)blk * FIN + tid];
    __syncthreads();
    if (tid < MIDD) {
        int h = tid;
        float s = b1[h];
#pragma unroll
        for (int f = 0; f < FIN; ++f) s = fmaf(x[f], W1[f * MIDD + h], s);
        A[(size_t)blk * MIDD + h] = s;
    } else {
        int h = tid - MIDD;   // 0..95
        float s = 0.f;
#pragma unroll
        for (int f = 0; f < FIN; ++f) s = fmaf(x[f], W1[(FIN + f) * MIDD + h], s);
        union { __hip_bfloat16 hh; unsigned short u; } cv;
        cv.hh = __float2bfloat16(s);
        Cb16[(size_t)blk * CPAD + h] = cv.u;
        if (h < CPAD - MIDD) Cb16[(size_t)blk * CPAD + MIDD + h] = 0;  // pad
    }
}

// ------------- main: (b, n-quad, m-half) blocks, partials out ----------------
__global__ __launch_bounds__(256, 3) void edge_main4(
    const float* __restrict__ edge,          // (B,N,255)
    const float* __restrict__ A,             // (B*N,96)
    const unsigned short* __restrict__ Cb16, // (B,N,CPAD) bf16
    const float* __restrict__ W1,            // row 128 used
    const unsigned short* __restrict__ W2T,  // (64,CPAD) bf16
    const float* __restrict__ b2,            // (64,)
    float* __restrict__ P)                   // (B*N, 2, 64) partial sums of r
{
    __shared__ unsigned short sC[HROWS * CPAD];   // 26832 B

    int bid = blockIdx.x;             // 0..1023
    int half = bid & 1;
    int rest = bid >> 1;              // 0..511
    int b = rest >> 6;
    int n0 = (rest & 63) << 2;
    int tid = threadIdx.x;
    int w = tid >> 6, lane = tid & 63;
    int lo16 = lane & 15, hi = lane >> 4;
    int mbase = half << 7;            // 0 or 128

    // stage C rows [mbase, mbase+HROWS) -> LDS (1677 uint4).
    // For half=1 / b=7 the last row reads 208 B past C (into W2T area) — never
    // consumed (half-1 js stop at 255), ws is large: safe.
    {
        const uint4* src = (const uint4*)(Cb16 + ((size_t)b * NN + mbase) * CPAD);
        uint4* dst = (uint4*)sC;
#pragma unroll
        for (int i = 0; i < 6; ++i) dst[i * 256 + tid] = src[i * 256 + tid];
        if (tid < 1677 - 6 * 256) dst[6 * 256 + tid] = src[6 * 256 + tid];
    }

    // per-lane k-slices of W1[128]: k = ks*32 + hi*8 + 0..7
    float W24[24];
    {
        const float* Wbase = W1 + 128 * MIDD;
#pragma unroll
        for (int ks = 0; ks < 3; ++ks) {
            int k0 = ks * 32 + hi * 8;
            float4 w0 = *(const float4*)(Wbase + k0);
            float4 w1 = *(const float4*)(Wbase + k0 + 4);
            W24[ks*8+0]=w0.x; W24[ks*8+1]=w0.y; W24[ks*8+2]=w0.z; W24[ks*8+3]=w0.w;
            W24[ks*8+4]=w1.x; W24[ks*8+5]=w1.y; W24[ks*8+6]=w1.z; W24[ks*8+7]=w1.w;
        }
    }

    // B fragments from global W2T (one-time, L2-resident)
    short8 bf[4][3];
#pragma unroll
    for (int nt = 0; nt < 4; ++nt)
#pragma unroll
        for (int ks = 0; ks < 3; ++ks)
            bf[nt][ks] = *(const short8*)&W2T[(nt * 16 + lo16) * CPAD + ks * 32 + hi * 8];

    float c2[4], corr[4];
#pragma unroll
    for (int nt = 0; nt < 4; ++nt) {
        c2[nt] = TWO_LOG2E * b2[nt * 16 + lo16];
        corr[nt] = 0.5f - RCPF(1.f + EXP2F(c2[nt]));
    }

    __syncthreads();

    float Rs[NG][4];
#pragma unroll
    for (int nl = 0; nl < NG; ++nl)
#pragma unroll
        for (int nt = 0; nt < 4; ++nt) Rs[nl][nt] = 0.f;

#pragma unroll 1
    for (int nl = 0; nl < NG; ++nl) {
        int n = n0 + nl;
        int bn = (b << 8) + n;

        float A24[24];
        {
            const float* Abase = A + (size_t)bn * MIDD;
#pragma unroll
            for (int ks = 0; ks < 3; ++ks) {
                int k0 = ks * 32 + hi * 8;
                float4 a0 = *(const float4*)(Abase + k0);
                float4 a1 = *(const float4*)(Abase + k0 + 4);
                A24[ks*8+0]=a0.x; A24[ks*8+1]=a0.y; A24[ks*8+2]=a0.z; A24[ks*8+3]=a0.w;
                A24[ks*8+4]=a1.x; A24[ks*8+5]=a1.y; A24[ks*8+6]=a1.z; A24[ks*8+7]=a1.w;
            }
        }
        const float* eg = edge + (size_t)bn * (NN - 1);

        // prefetch both chunks' edge values
        float ev[2];
#pragma unroll
        for (int c = 0; c < 2; ++c) {
            int m = mbase + c * 64 + w * 16 + lo16;
            ev[c] = eg[m < NN - 1 ? m : NN - 2];
        }

#pragma unroll
        for (int chunk = 0; chunk < 2; ++chunk) {
            int m = mbase + chunk * 64 + w * 16 + lo16;
            bool valid = (m < NN - 1);
            unsigned mc = valid ? 0xFFFFFFFFu : 0u;
            int j = m + ((m >= n) ? 1 : 0);
            j = (j > 255) ? 255 : j;
            float e = ev[chunk];
            const unsigned short* crow = &sC[(j - mbase) * CPAD + hi * 8];

            short8 af[3];
#pragma unroll
            for (int ks = 0; ks < 3; ++ks) {
                uint4 q = *(const uint4*)(crow + ks * 32);   // ds_read_b128
                float c[8];
                c[0] = __uint_as_float(q.x << 16);
                c[1] = __uint_as_float(q.x & 0xFFFF0000u);
                c[2] = __uint_as_float(q.y << 16);
                c[3] = __uint_as_float(q.y & 0xFFFF0000u);
                c[4] = __uint_as_float(q.z << 16);
                c[5] = __uint_as_float(q.z & 0xFFFF0000u);
                c[6] = __uint_as_float(q.w << 16);
                c[7] = __uint_as_float(q.w & 0xFFFF0000u);
                float h[8];
#pragma unroll
                for (int i = 0; i < 8; ++i)
                    h[i] = fmaxf(fmaf(e, W24[ks*8+i], A24[ks*8+i] + c[i]), 0.f);
                union { unsigned u[4]; short8 s; } cv;
                cv.u[0] = pack_bf16(h[0], h[1]) & mc;
                cv.u[1] = pack_bf16(h[2], h[3]) & mc;
                cv.u[2] = pack_bf16(h[4], h[5]) & mc;
                cv.u[3] = pack_bf16(h[6], h[7]) & mc;
                af[ks] = cv.s;
            }

            f32x4 acc[4] = {{0.f,0.f,0.f,0.f},{0.f,0.f,0.f,0.f},
                            {0.f,0.f,0.f,0.f},{0.f,0.f,0.f,0.f}};
#pragma unroll
            for (int ks = 0; ks < 3; ++ks)
#pragma unroll
                for (int nt = 0; nt < 4; ++nt)
                    acc[nt] = __builtin_amdgcn_mfma_f32_16x16x32_bf16(
                        af[ks], bf[nt][ks], acc[nt], 0, 0, 0);

#pragma unroll
            for (int nt = 0; nt < 4; ++nt)
#pragma unroll
                for (int r4 = 0; r4 < 4; ++r4) {
                    float arg = fmaf(acc[nt][r4], TWO_LOG2E, c2[nt]);
                    Rs[nl][nt] += RCPF(1.f + EXP2F(arg));
                }
        }

        // invalid slot m=255 lives in half1/chunk1, D-row 15 (w=3,hi=3)
        if (half == 1 && w == 3 && hi == 3) {
#pragma unroll
            for (int nt = 0; nt < 4; ++nt) Rs[nl][nt] += corr[nt];
        }
    }

    // ---- reduce + write partials; overlay reduce scratch on sC ----
    __syncthreads();
    float* s_red = (float*)sC;   // [NG][4 waves][64] = 4 KB
#pragma unroll
    for (int nl = 0; nl < NG; ++nl)
#pragma unroll
        for (int nt = 0; nt < 4; ++nt) {
            float v = Rs[nl][nt];
            v += __shfl_xor(v, 16);
            v += __shfl_xor(v, 32);
            Rs[nl][nt] = v;
        }
    if (hi == 0) {
#pragma unroll
        for (int nl = 0; nl < NG; ++nl)
#pragma unroll
            for (int nt = 0; nt < 4; ++nt)
                s_red[(nl * 4 + w) * 64 + nt * 16 + lo16] = Rs[nl][nt];
    }
    __syncthreads();
    {
        int onl = tid >> 6, oo = tid & 63;
        float t = s_red[(onl * 4 + 0) * 64 + oo] + s_red[(onl * 4 + 1) * 64 + oo]
                + s_red[(onl * 4 + 2) * 64 + oo] + s_red[(onl * 4 + 3) * 64 + oo];
        P[((size_t)((b << 8) + n0 + onl) * 2 + half) * 64 + oo] = t;
    }
}

// ------------- combine: out = 256 - 2*(P0 + P1) ------------------------------
__global__ __launch_bounds__(256) void edge_comb(
    const float* __restrict__ P,   // (B*N, 2, 64)
    float* __restrict__ out)       // (B*N, 64)
{
    int idx = blockIdx.x * 256 + threadIdx.x;   // 0..131071
    int bn = idx >> 6, o = idx & 63;
    float t = P[(size_t)bn * 128 + o] + P[(size_t)bn * 128 + 64 + o];
    out[idx] = fmaf(-2.f, t, 256.f);
}

extern "C" void kernel_launch(void* const* d_in, const int* in_sizes, int n_in,
                              void* d_out, int out_size, void* d_ws, size_t ws_size,
                              hipStream_t stream) {
    const float* inp_node = (const float*)d_in[0];  // (8,256,64)
    const float* inp_edge = (const float*)d_in[1];  // (8,256,255)
    const float* W1       = (const float*)d_in[2];  // (129,96)
    const float* b1       = (const float*)d_in[3];  // (96,)
    const float* W2       = (const float*)d_in[4];  // (96,64)
    const float* b2       = (const float*)d_in[5];  // (64,)
    float* out            = (float*)d_out;          // (8,256,64)

    float* A = (float*)d_ws;                                        // 786 KB
    unsigned short* Cb16 = (unsigned short*)(A + (size_t)BATCH * NN * MIDD); // 426 KB
    unsigned short* W2T  = Cb16 + (size_t)BATCH * NN * CPAD;        // 13.3 KB
    float* P = (float*)(W2T + (size_t)FOUT * CPAD);                 // 1 MB

    edge_pre<<<BATCH * NN + 1, 192, 0, stream>>>(inp_node, W1, b1, W2, A, Cb16, W2T);
    edge_main4<<<BATCH * (NN / NG) * 2, 256, 0, stream>>>(inp_edge, A, Cb16, W1, W2T, b2, P);
    edge_comb<<<BATCH * NN * FOUT / 256, 256, 0, stream>>>(P, out);
}

// Round 10
// 38.297 us; speedup vs baseline: 1.0934x; 1.0934x over previous
//
#include <hip/hip_runtime.h>
#include <hip/hip_bf16.h>

// EdgeNetwork: B=8, N=256, F_IN=64, F_OUT=64, MID=96
// out[b,n,o] = sum_m tanh( relu( [x_n, x_j(m), e_{b,n,m}] @ W1 + b1 ) @ W2 + b2 )[o]
// H[m,:] = A[b,n,:] + C[b,j(m),:] + e[m]*W1[128,:],  j = m + (m>=n)
// R10: R8 single-kernel shape + v_pk_add/fma_f32 packed H-build + explicit
// register double-buffering of C-slices (ds) and A-rows (global) + mask hoist.
// tanh(v) = 1 - 2r, r = 1/(1+exp(2v));  out = 256 - 2*sum(r), invalid slot -> 0.5.

#define BATCH 8
#define NN 256
#define FIN 64
#define FOUT 64
#define MIDD 96
#define CPAD 104   // bf16 elems per padded row (208 B)
#define NG 4       // n-values per block

typedef __attribute__((ext_vector_type(8))) short short8;  // 8 bf16
typedef __attribute__((ext_vector_type(4))) float f32x4;
typedef __attribute__((ext_vector_type(2))) float f32x2;

#if __has_builtin(__builtin_amdgcn_exp2f)
#define EXP2F(x) __builtin_amdgcn_exp2f(x)
#else
#define EXP2F(x) exp2f(x)
#endif
#if __has_builtin(__builtin_amdgcn_rcpf)
#define RCPF(x) __builtin_amdgcn_rcpf(x)
#else
#define RCPF(x) (1.0f / (x))
#endif

#define TWO_LOG2E 2.8853900817779268f

__device__ __forceinline__ f32x2 pk_add(f32x2 a, f32x2 b) {
    f32x2 d;
    asm("v_pk_add_f32 %0, %1, %2" : "=v"(d) : "v"(a), "v"(b));
    return d;
}
__device__ __forceinline__ f32x2 pk_fma(f32x2 a, f32x2 b, f32x2 c) {
    f32x2 d;
    asm("v_pk_fma_f32 %0, %1, %2, %3" : "=v"(d) : "v"(a), "v"(b), "v"(c));
    return d;
}

__device__ __forceinline__ unsigned pack_bf16(float lo, float hi) {
    __hip_bfloat162 h2 = __float22bfloat162_rn(make_float2(lo, hi));
    union { __hip_bfloat162 h; unsigned u; } cv; cv.h = h2;
    return cv.u;
}

// ------------- precompute: A (f32), C (bf16 padded), W2T (bf16 padded) -------
__global__ __launch_bounds__(192) void edge_pre(
    const float* __restrict__ node,    // (B,N,64)
    const float* __restrict__ W1,      // (129,96)
    const float* __restrict__ b1,      // (96,)
    const float* __restrict__ W2,      // (96,64)
    float* __restrict__ A,             // (B*N,96) f32
    unsigned short* __restrict__ Cb16, // (B,N,CPAD) bf16
    unsigned short* __restrict__ W2T)  // (64,CPAD) bf16
{
    int blk = blockIdx.x;
    int tid = threadIdx.x;
    if (blk == BATCH * NN) {
        for (int idx = tid; idx < FOUT * CPAD; idx += 192) {
            int c = idx / CPAD, k = idx % CPAD;
            float v = (k < MIDD) ? W2[k * FOUT + c] : 0.f;
            union { __hip_bfloat16 h; unsigned short u; } cv;
            cv.h = __float2bfloat16(v);
            W2T[idx] = cv.u;
        }
        return;
    }
    __shared__ float x[FIN];
    if (tid < FIN) x[tid] = node[(size_t)blk * FIN + tid];
    __syncthreads();
    if (tid < MIDD) {
        int h = tid;
        float s = b1[h];
#pragma unroll
        for (int f = 0; f < FIN; ++f) s = fmaf(x[f], W1[f * MIDD + h], s);
        A[(size_t)blk * MIDD + h] = s;
    } else {
        int h = tid - MIDD;   // 0..95
        float s = 0.f;
#pragma unroll
        for (int f = 0; f < FIN; ++f) s = fmaf(x[f], W1[(FIN + f) * MIDD + h], s);
        union { __hip_bfloat16 hh; unsigned short u; } cv;
        cv.hh = __float2bfloat16(s);
        Cb16[(size_t)blk * CPAD + h] = cv.u;
        if (h < CPAD - MIDD) Cb16[(size_t)blk * CPAD + MIDD + h] = 0;  // pad
    }
}

// ------------- main: LDS-staged C[b], packed math, reg double-buffering ------
__global__ __launch_bounds__(256, 2) void edge_main5(
    const float* __restrict__ edge,          // (B,N,255)
    const float* __restrict__ A,             // (B*N,96)
    const unsigned short* __restrict__ Cb16, // (B,N,CPAD) bf16
    const float* __restrict__ W1,            // row 128 used
    const unsigned short* __restrict__ W2T,  // (64,CPAD) bf16
    const float* __restrict__ b2,            // (64,)
    float* __restrict__ out)                 // (B,N,64)
{
    __shared__ unsigned short sC[NN * CPAD];   // 53248 B; tail reused for reduce

    int blk = blockIdx.x;             // 0..511
    int b = blk >> 6;
    int n0 = (blk & 63) << 2;
    int tid = threadIdx.x;
    int w = tid >> 6, lane = tid & 63;
    int lo16 = lane & 15, hi = lane >> 4;

    // stage C[b] -> LDS, fully coalesced (3328 uint4)
    {
        const uint4* src = (const uint4*)(Cb16 + (size_t)b * NN * CPAD);
        uint4* dst = (uint4*)sC;
#pragma unroll
        for (int i = 0; i < 13; ++i) dst[i * 256 + tid] = src[i * 256 + tid];
    }

    // W1[128] slices as f32x2 pairs: pair p of ks covers k = ks*32+hi*8+2p..+1
    f32x2 W2p[12];
    {
        const float* Wbase = W1 + 128 * MIDD;
#pragma unroll
        for (int ks = 0; ks < 3; ++ks) {
            int k0 = ks * 32 + hi * 8;
            float4 w0 = *(const float4*)(Wbase + k0);
            float4 w1 = *(const float4*)(Wbase + k0 + 4);
            W2p[ks*4+0] = f32x2{w0.x, w0.y};
            W2p[ks*4+1] = f32x2{w0.z, w0.w};
            W2p[ks*4+2] = f32x2{w1.x, w1.y};
            W2p[ks*4+3] = f32x2{w1.z, w1.w};
        }
    }

    // B fragments from global W2T (one-time, L2-resident)
    short8 bf[4][3];
#pragma unroll
    for (int nt = 0; nt < 4; ++nt)
#pragma unroll
        for (int ks = 0; ks < 3; ++ks)
            bf[nt][ks] = *(const short8*)&W2T[(nt * 16 + lo16) * CPAD + ks * 32 + hi * 8];

    float c2[4], corr[4];
#pragma unroll
    for (int nt = 0; nt < 4; ++nt) {
        c2[nt] = TWO_LOG2E * b2[nt * 16 + lo16];
        corr[nt] = 0.5f - RCPF(1.f + EXP2F(c2[nt]));
    }

    __syncthreads();

    float Rs[NG][4];
#pragma unroll
    for (int nl = 0; nl < NG; ++nl)
#pragma unroll
        for (int nt = 0; nt < 4; ++nt) Rs[nl][nt] = 0.f;

    // A-row double buffer (global loads issued one nl ahead)
    float4 Ab[6];
    {
        const float* Abase = A + (size_t)((b << 8) + n0) * MIDD;
#pragma unroll
        for (int ks = 0; ks < 3; ++ks) {
            int k0 = ks * 32 + hi * 8;
            Ab[ks*2+0] = *(const float4*)(Abase + k0);
            Ab[ks*2+1] = *(const float4*)(Abase + k0 + 4);
        }
    }

#pragma unroll 1
    for (int nl = 0; nl < NG; ++nl) {
        int n = n0 + nl;
        int bn = (b << 8) + n;

        // unpack current A into pairs, then issue next nl's loads
        f32x2 A2[12];
#pragma unroll
        for (int ks = 0; ks < 3; ++ks) {
            float4 a0 = Ab[ks*2+0], a1 = Ab[ks*2+1];
            A2[ks*4+0] = f32x2{a0.x, a0.y};
            A2[ks*4+1] = f32x2{a0.z, a0.w};
            A2[ks*4+2] = f32x2{a1.x, a1.y};
            A2[ks*4+3] = f32x2{a1.z, a1.w};
        }
        if (nl < NG - 1) {
            const float* Abase = A + (size_t)(bn + 1) * MIDD;
#pragma unroll
            for (int ks = 0; ks < 3; ++ks) {
                int k0 = ks * 32 + hi * 8;
                Ab[ks*2+0] = *(const float4*)(Abase + k0);
                Ab[ks*2+1] = *(const float4*)(Abase + k0 + 4);
            }
        }

        const float* eg = edge + (size_t)bn * (NN - 1);
        // prefetch all 4 chunks' edge values
        float ev[4];
#pragma unroll
        for (int c = 0; c < 4; ++c) {
            int m = c * 64 + w * 16 + lo16;
            ev[c] = eg[m < NN - 1 ? m : NN - 2];
        }

        // C-slice register double buffer: q = current chunk's 3 b128 reads
        uint4 q0, q1, q2;
        {
            int m = w * 16 + lo16;
            int j = m + (m >= n);
            const unsigned short* crow = &sC[j * CPAD + hi * 8];
            q0 = *(const uint4*)(crow);
            q1 = *(const uint4*)(crow + 32);
            q2 = *(const uint4*)(crow + 64);
        }

#pragma unroll
        for (int chunk = 0; chunk < 4; ++chunk) {
            uint4 n0q, n1q, n2q;
            if (chunk < 3) {
                int mn = (chunk + 1) * 64 + w * 16 + lo16;
                int jn = mn + (mn >= n);
                if (chunk + 1 == 3) jn = (jn > 255) ? 255 : jn;
                const unsigned short* crow = &sC[jn * CPAD + hi * 8];
                n0q = *(const uint4*)(crow);
                n1q = *(const uint4*)(crow + 32);
                n2q = *(const uint4*)(crow + 64);
            }

            f32x2 e2 = f32x2{ev[chunk], ev[chunk]};
            uint4 qs[3] = {q0, q1, q2};

            short8 af[3];
#pragma unroll
            for (int ks = 0; ks < 3; ++ks) {
                unsigned uu[4] = {qs[ks].x, qs[ks].y, qs[ks].z, qs[ks].w};
                unsigned ro[4];
#pragma unroll
                for (int p = 0; p < 4; ++p) {
                    f32x2 c;
                    c.x = __uint_as_float(uu[p] << 16);
                    c.y = __uint_as_float(uu[p] & 0xFFFF0000u);
                    f32x2 s = pk_add(A2[ks*4+p], c);
                    f32x2 h = pk_fma(e2, W2p[ks*4+p], s);
                    ro[p] = pack_bf16(fmaxf(h.x, 0.f), fmaxf(h.y, 0.f));
                }
                union { unsigned u[4]; short8 s8; } cv;
                cv.u[0] = ro[0]; cv.u[1] = ro[1]; cv.u[2] = ro[2]; cv.u[3] = ro[3];
                af[ks] = cv.s8;
            }

            // invalid slot: m=255 -> row lo16==15 of wave 3, chunk 3 only
            if (chunk == 3 && w == 3 && lo16 == 15) {
                af[0] = (short8)0; af[1] = (short8)0; af[2] = (short8)0;
            }

            f32x4 acc[4] = {{0.f,0.f,0.f,0.f},{0.f,0.f,0.f,0.f},
                            {0.f,0.f,0.f,0.f},{0.f,0.f,0.f,0.f}};
#pragma unroll
            for (int ks = 0; ks < 3; ++ks)
#pragma unroll
                for (int nt = 0; nt < 4; ++nt)
                    acc[nt] = __builtin_amdgcn_mfma_f32_16x16x32_bf16(
                        af[ks], bf[nt][ks], acc[nt], 0, 0, 0);

#pragma unroll
            for (int nt = 0; nt < 4; ++nt)
#pragma unroll
                for (int r4 = 0; r4 < 4; ++r4) {
                    float arg = fmaf(acc[nt][r4], TWO_LOG2E, c2[nt]);
                    Rs[nl][nt] += RCPF(1.f + EXP2F(arg));
                }

            if (chunk < 3) { q0 = n0q; q1 = n1q; q2 = n2q; }
        }

        // invalid slot correction (D-row 15 = lanes hi==3, wave 3)
        if (w == 3 && hi == 3) {
#pragma unroll
            for (int nt = 0; nt < 4; ++nt) Rs[nl][nt] += corr[nt];
        }
    }

    // ---- final reduction: overlay on sC (all sC reads are done) ----
    __syncthreads();
    float* s_red = (float*)sC;   // [NG][4 waves][64] = 4 KB
#pragma unroll
    for (int nl = 0; nl < NG; ++nl)
#pragma unroll
        for (int nt = 0; nt < 4; ++nt) {
            float v = Rs[nl][nt];
            v += __shfl_xor(v, 16);
            v += __shfl_xor(v, 32);
            Rs[nl][nt] = v;
        }
    if (hi == 0) {
#pragma unroll
        for (int nl = 0; nl < NG; ++nl)
#pragma unroll
            for (int nt = 0; nt < 4; ++nt)
                s_red[(nl * 4 + w) * 64 + nt * 16 + lo16] = Rs[nl][nt];
    }
    __syncthreads();
    {
        int onl = tid >> 6, oo = tid & 63;   // 256 threads = 4 nl x 64 cols
        float t = s_red[(onl * 4 + 0) * 64 + oo] + s_red[(onl * 4 + 1) * 64 + oo]
                + s_red[(onl * 4 + 2) * 64 + oo] + s_red[(onl * 4 + 3) * 64 + oo];
        out[(size_t)((b << 8) + n0 + onl) * FOUT + oo] = fmaf(-2.f, t, 256.f);
    }
}

extern "C" void kernel_launch(void* const* d_in, const int* in_sizes, int n_in,
                              void* d_out, int out_size, void* d_ws, size_t ws_size,
                              hipStream_t stream) {
    const float* inp_node = (const float*)d_in[0];  // (8,256,64)
    const float* inp_edge = (const float*)d_in[1];  // (8,256,255)
    const float* W1       = (const float*)d_in[2];  // (129,96)
    const float* b1       = (const float*)d_in[3];  // (96,)
    const float* W2       = (const float*)d_in[4];  // (96,64)
    const float* b2       = (const float*)d_in[5];  // (64,)
    float* out            = (float*)d_out;          // (8,256,64)

    float* A = (float*)d_ws;                                        // 2048*96 f32
    unsigned short* Cb16 = (unsigned short*)(A + (size_t)BATCH * NN * MIDD); // 2048*CPAD bf16
    unsigned short* W2T  = Cb16 + (size_t)BATCH * NN * CPAD;        // 64*CPAD bf16

    edge_pre<<<BATCH * NN + 1, 192, 0, stream>>>(inp_node, W1, b1, W2, A, Cb16, W2T);
    edge_main5<<<BATCH * (NN / NG), 256, 0, stream>>>(inp_edge, A, Cb16, W1, W2T, b2, out);
}